// Round 5
// baseline (601.062 us; speedup 1.0000x reference)
//
#include <hip/hip_runtime.h>
#include <math.h>

#define NT 256

__device__ __forceinline__ float rlf(float v, int l) {
    return __int_as_float(__builtin_amdgcn_readlane(__float_as_int(v), l));
}
__device__ __forceinline__ int rli(int v, int l) {
    return __builtin_amdgcn_readlane(v, l);
}
__device__ __forceinline__ int imin(int a, int b) { return a < b ? a : b; }
__device__ __forceinline__ int imax(int a, int b) { return a > b ? a : b; }

// ---------------- CSR build ----------------

__global__ void zero_i32(int* __restrict__ p, int n) {
    int t = blockIdx.x * blockDim.x + threadIdx.x;
    if (t < n) p[t] = 0;
}

__global__ void hist_dst(int* __restrict__ cnt, const int* __restrict__ dst, int n_edges) {
    int e = blockIdx.x * blockDim.x + threadIdx.x;
    if (e < n_edges) atomicAdd(&cnt[dst[e]], 1);
}

// single-block exclusive scan of cnt[0..n) -> row_off[0..n], cursor[0..n)
__global__ void scan_offsets(const int* __restrict__ cnt, int* __restrict__ row_off,
                             int* __restrict__ cursor, int n) {
    __shared__ int tsum[1024];
    int tid = threadIdx.x;
    int chunk = (n + 1023) / 1024;
    int beg = tid * chunk;
    int end = beg + chunk; if (end > n) end = n;
    int s = 0;
    for (int i = beg; i < end; ++i) s += cnt[i];
    tsum[tid] = s;
    __syncthreads();
    for (int off = 1; off < 1024; off <<= 1) {
        int v = (tid >= off) ? tsum[tid - off] : 0;
        __syncthreads();
        tsum[tid] += v;
        __syncthreads();
    }
    int run = (tid == 0) ? 0 : tsum[tid - 1];
    for (int i = beg; i < end; ++i) {
        row_off[i] = run;
        cursor[i] = run;
        run += cnt[i];
    }
    if (tid == 1023) row_off[n] = tsum[1023];
}

__global__ void edge_scatter(int* __restrict__ csr_src, int* __restrict__ cursor,
                             const int* __restrict__ src, const int* __restrict__ dst,
                             int n_edges) {
    int e = blockIdx.x * blockDim.x + threadIdx.x;
    if (e < n_edges) {
        int p = atomicAdd(&cursor[dst[e]], 1);
        csr_src[p] = src[e];
    }
}

// ---------------- pooling helpers ----------------

__global__ void pool_init(float* __restrict__ pooled, int n) {
    int t = blockIdx.x * blockDim.x + threadIdx.x;
    if (t < n) pooled[t] = -INFINITY;
}

__device__ __forceinline__ void atomicMaxFloat(float* addr, float value) {
    if (value >= 0.0f)
        atomicMax((int*)addr, __float_as_int(value));
    else
        atomicMin((unsigned int*)addr, (unsigned int)__float_as_int(value));
}

// ---------------- fused SAGE layer ----------------
// Persistent waves; 4 nodes per wave-iteration.
// Fast path (all degs <= 64, full quad): all 4 index vectors loaded once,
// gathers issued 32-deep (8 per node interleaved) with SGPR-base addressing,
// tail handled by a single uniform correction fma instead of per-edge selects.
// Dense: weights in LDS [k4][lane][4] (conflict-free ds_read_b128),
// multiplier broadcast via v_readlane.
__global__ __launch_bounds__(NT, 5) void sage_layer(
    float* __restrict__ out, float* __restrict__ pooled,
    const float* __restrict__ h_in,
    const int* __restrict__ row_off, const int* __restrict__ csr_src,
    const int* __restrict__ batch,
    const float* __restrict__ Wl, const float* __restrict__ Wr,
    const float* __restrict__ bl,
    int n_nodes, int n_edges, int do_pool) {
    __shared__ float WL[4096];  // WL[k4*256 + f*4 + kk] = Wl[f][k4*4+kk]
    __shared__ float WR[4096];
    int tid = threadIdx.x;
    for (int t = tid; t < 4096; t += NT) {
        int kk = t & 3, f = (t >> 2) & 63, k4 = t >> 8;
        WL[t] = Wl[f * 64 + k4 * 4 + kk];
        WR[t] = Wr[f * 64 + k4 * 4 + kk];
    }
    __syncthreads();

    int lane = tid & 63;
    int gwave = (blockIdx.x * NT + tid) >> 6;
    int nwaves = (gridDim.x * NT) >> 6;
    float bias = bl[lane];

    for (int q = gwave; q * 4 < n_nodes; q += nwaves) {
        int base = q * 4;
        bool quad_ok = (base + 4 <= n_nodes);

        int b0 = 0, b1 = 0, b2 = 0, b3 = 0;
        int d0 = 0, d1 = 0, d2 = 0, d3 = 0;
        if (quad_ok) {
            int ro = row_off[base + (lane < 4 ? lane : 4)];
            b0 = rli(ro, 0); b1 = rli(ro, 1); b2 = rli(ro, 2); b3 = rli(ro, 3);
            int e3v = rli(ro, 4);
            d0 = b1 - b0; d1 = b2 - b1; d2 = b3 - b2; d3 = e3v - b3;
        }
        int dmax = imax(imax(d0, d1), imax(d2, d3));

        float mean0 = 0.f, mean1 = 0.f, mean2 = 0.f, mean3 = 0.f;
        float hv0 = 0.f, hv1 = 0.f, hv2 = 0.f, hv3 = 0.f;

        if (quad_ok && dmax <= 64) {
            // ---- fast path ----
            hv0 = h_in[(size_t)(base + 0) * 64 + lane];
            hv1 = h_in[(size_t)(base + 1) * 64 + lane];
            hv2 = h_in[(size_t)(base + 2) * 64 + lane];
            hv3 = h_in[(size_t)(base + 3) * 64 + lane];
            // clamped coalesced index-vector loads (safe for deg==0 rows)
            int c0 = imin(imax(b0 + imin(lane, d0 - 1), 0), n_edges - 1);
            int c1 = imin(imax(b1 + imin(lane, d1 - 1), 0), n_edges - 1);
            int c2 = imin(imax(b2 + imin(lane, d2 - 1), 0), n_edges - 1);
            int c3 = imin(imax(b3 + imin(lane, d3 - 1), 0), n_edges - 1);
            int idx0 = csr_src[c0];
            int idx1 = csr_src[c1];
            int idx2 = csr_src[c2];
            int idx3 = csr_src[c3];

            float a0 = 0.f, a1 = 0.f, a2 = 0.f, a3 = 0.f;
            for (int j = 0; j < dmax; j += 8) {
                float v00, v01, v02, v03, v04, v05, v06, v07;
                float v10, v11, v12, v13, v14, v15, v16, v17;
                float v20, v21, v22, v23, v24, v25, v26, v27;
                float v30, v31, v32, v33, v34, v35, v36, v37;
#define ISSUE8(n)                                                             \
                if (j < d##n) {                                               \
                    int dm1 = d##n - 1;                                       \
                    v##n##0 = h_in[(size_t)rli(idx##n, j) * 64 + lane];       \
                    v##n##1 = h_in[(size_t)rli(idx##n, imin(j+1,dm1))*64+lane];\
                    v##n##2 = h_in[(size_t)rli(idx##n, imin(j+2,dm1))*64+lane];\
                    v##n##3 = h_in[(size_t)rli(idx##n, imin(j+3,dm1))*64+lane];\
                    v##n##4 = h_in[(size_t)rli(idx##n, imin(j+4,dm1))*64+lane];\
                    v##n##5 = h_in[(size_t)rli(idx##n, imin(j+5,dm1))*64+lane];\
                    v##n##6 = h_in[(size_t)rli(idx##n, imin(j+6,dm1))*64+lane];\
                    v##n##7 = h_in[(size_t)rli(idx##n, imin(j+7,dm1))*64+lane];\
                }
                ISSUE8(0)
                ISSUE8(1)
                ISSUE8(2)
                ISSUE8(3)
#undef ISSUE8
#define CONSUME8(n)                                                           \
                if (j < d##n) {                                               \
                    float s8 = ((v##n##0 + v##n##1) + (v##n##2 + v##n##3))    \
                             + ((v##n##4 + v##n##5) + (v##n##6 + v##n##7));   \
                    a##n += s8;                                               \
                    int over = j + 8 - d##n;                                  \
                    if (over > 0) a##n -= (float)over * v##n##7;              \
                }
                CONSUME8(0)
                CONSUME8(1)
                CONSUME8(2)
                CONSUME8(3)
#undef CONSUME8
            }
            mean0 = a0 * (1.0f / (float)(d0 > 0 ? d0 : 1));
            mean1 = a1 * (1.0f / (float)(d1 > 0 ? d1 : 1));
            mean2 = a2 * (1.0f / (float)(d2 > 0 ? d2 : 1));
            mean3 = a3 * (1.0f / (float)(d3 > 0 ? d3 : 1));
        } else {
            // ---- generic slow path (ragged tail quad or deg > 64) ----
#define GATHER_NODE(MEAN, HV, N)                                              \
            {                                                                 \
                int i = base + (N);                                           \
                if (i < n_nodes) {                                            \
                    int beg = row_off[i];                                     \
                    int end_ = row_off[i + 1];                                \
                    int deg = end_ - beg;                                     \
                    float aa = 0.f;                                           \
                    for (int cb = beg; cb < end_; cb += 64) {                 \
                        int m = end_ - cb; if (m > 64) m = 64;                \
                        int lidx = cb + (lane < m ? lane : m - 1);            \
                        int idx = csr_src[lidx];                              \
                        for (int j = 0; j < m; ++j)                           \
                            aa += h_in[(size_t)rli(idx, j) * 64 + lane];      \
                    }                                                         \
                    MEAN = aa * (1.0f / (float)(deg > 0 ? deg : 1));          \
                    HV = h_in[(size_t)i * 64 + lane];                         \
                }                                                             \
            }
            GATHER_NODE(mean0, hv0, 0)
            GATHER_NODE(mean1, hv1, 1)
            GATHER_NODE(mean2, hv2, 2)
            GATHER_NODE(mean3, hv3, 3)
#undef GATHER_NODE
        }

        float o0 = bias, o1 = bias, o2 = bias, o3 = bias;
        for (int k4 = 0; k4 < 16; ++k4) {
            float4 wl = *(const float4*)&WL[k4 * 256 + lane * 4];
            float4 wr = *(const float4*)&WR[k4 * 256 + lane * 4];
            int kb = k4 * 4;
#define DENSE_KK(WLK, WRK, KK)                                                \
            {                                                                 \
                int k = kb + (KK);                                            \
                o0 += rlf(mean0, k) * (WLK) + rlf(hv0, k) * (WRK);            \
                o1 += rlf(mean1, k) * (WLK) + rlf(hv1, k) * (WRK);            \
                o2 += rlf(mean2, k) * (WLK) + rlf(hv2, k) * (WRK);            \
                o3 += rlf(mean3, k) * (WLK) + rlf(hv3, k) * (WRK);            \
            }
            DENSE_KK(wl.x, wr.x, 0)
            DENSE_KK(wl.y, wr.y, 1)
            DENSE_KK(wl.z, wr.z, 2)
            DENSE_KK(wl.w, wr.w, 3)
#undef DENSE_KK
        }

        o0 = tanhf(o0); o1 = tanhf(o1); o2 = tanhf(o2); o3 = tanhf(o3);

#define WRITE_NODE(O, N)                                                      \
        {                                                                     \
            int i = base + (N);                                               \
            if (i < n_nodes) {                                                \
                if (do_pool) {                                                \
                    atomicMaxFloat(&pooled[(size_t)batch[i] * 64 + lane], O); \
                } else {                                                      \
                    out[(size_t)i * 64 + lane] = O;                           \
                }                                                             \
            }                                                                 \
        }
        WRITE_NODE(o0, 0)
        WRITE_NODE(o1, 1)
        WRITE_NODE(o2, 2)
        WRITE_NODE(o3, 3)
#undef WRITE_NODE
    }
}

// ---------------- MLP head ----------------
__global__ void head(float* __restrict__ out, const float* __restrict__ pooled,
                     const float* __restrict__ W1, const float* __restrict__ b1,
                     const float* __restrict__ W2, const float* __restrict__ b2) {
    __shared__ float W1T[64][64];
    int tid = threadIdx.x;
    for (int t = tid; t < 4096; t += NT) {
        int f = t >> 6, k = t & 63;
        W1T[k][f] = W1[t];
    }
    __syncthreads();

    int lane = tid & 63;
    int g = blockIdx.x * (NT >> 6) + (tid >> 6);
    float v = pooled[(size_t)g * 64 + lane];
    float bias = b1[lane];
#pragma unroll
    for (int it = 0; it < 3; ++it) {
        float acc = bias;
#pragma unroll
        for (int k = 0; k < 64; ++k) {
            acc += rlf(v, k) * W1T[k][lane];
        }
        v = tanhf(acc);
    }
#pragma unroll
    for (int j = 0; j < 3; ++j) {
        float p = v * W2[j * 64 + lane];
#pragma unroll
        for (int off = 32; off >= 1; off >>= 1) p += __shfl_xor(p, off);
        if (lane == 0) out[g * 3 + j] = p + b2[j];
    }
}

// ---------------- launch ----------------

extern "C" void kernel_launch(void* const* d_in, const int* in_sizes, int n_in,
                              void* d_out, int out_size, void* d_ws, size_t ws_size,
                              hipStream_t stream) {
    const float* x   = (const float*)d_in[0];
    const float* Wl0 = (const float*)d_in[1];
    const float* Wr0 = (const float*)d_in[2];
    const float* bl0 = (const float*)d_in[3];
    const float* Wl  = (const float*)d_in[4];
    const float* Wr  = (const float*)d_in[5];
    const float* bl  = (const float*)d_in[6];
    const float* W1  = (const float*)d_in[7];
    const float* b1  = (const float*)d_in[8];
    const float* W2  = (const float*)d_in[9];
    const float* b2  = (const float*)d_in[10];
    const int* ei    = (const int*)d_in[11];
    const int* batch = (const int*)d_in[12];

    int n_nodes = in_sizes[0] / 64;
    int n_edges = in_sizes[11] / 2;
    const int* src = ei;
    const int* dst = ei + n_edges;

    float* bufA   = (float*)d_ws;                         // n_nodes*64
    float* bufB   = bufA + (size_t)n_nodes * 64;          // n_nodes*64
    int* csr_src  = (int*)(bufB + (size_t)n_nodes * 64);  // n_edges
    int* row_off  = csr_src + n_edges;                    // n_nodes+1
    int* cursor   = row_off + (n_nodes + 1);              // n_nodes
    int* cnt      = cursor + n_nodes;                     // n_nodes
    float* pooled = (float*)(cnt + n_nodes);              // 128*64

    int eblk = (n_edges + NT - 1) / NT;
    int nblk = (n_nodes + NT - 1) / NT;
    const int pers_blk = 1280;  // 5 blocks/CU x 256 CUs (LDS allows exactly 5)

    // CSR build
    zero_i32<<<nblk, NT, 0, stream>>>(cnt, n_nodes);
    hist_dst<<<eblk, NT, 0, stream>>>(cnt, dst, n_edges);
    scan_offsets<<<1, 1024, 0, stream>>>(cnt, row_off, cursor, n_nodes);
    edge_scatter<<<eblk, NT, 0, stream>>>(csr_src, cursor, src, dst, n_edges);

    pool_init<<<(128 * 64 + NT - 1) / NT, NT, 0, stream>>>(pooled, 128 * 64);

    sage_layer<<<pers_blk, NT, 0, stream>>>(bufA, pooled, x, row_off, csr_src, batch,
                                            Wl0, Wr0, bl0, n_nodes, n_edges, 0);
    sage_layer<<<pers_blk, NT, 0, stream>>>(bufB, pooled, bufA, row_off, csr_src, batch,
                                            Wl, Wr, bl, n_nodes, n_edges, 0);
    sage_layer<<<pers_blk, NT, 0, stream>>>(bufA, pooled, bufB, row_off, csr_src, batch,
                                            Wl, Wr, bl, n_nodes, n_edges, 0);
    sage_layer<<<pers_blk, NT, 0, stream>>>(bufB, pooled, bufA, row_off, csr_src, batch,
                                            Wl, Wr, bl, n_nodes, n_edges, 1);

    head<<<32, NT, 0, stream>>>((float*)d_out, pooled, W1, b1, W2, b2);
}